// Round 15
// baseline (409.282 us; speedup 1.0000x reference)
//
#include <hip/hip_runtime.h>
#include <hip/hip_bf16.h>
#include <math.h>

#define NN 20000
#define EE 320000
#define PQ_COLS  384
#define PQP_COLS 288
#define PKP_COLS 288
#define QE_COLS  768
#define VE_COLS  672
#define KE_COLS  768
#define FCOLS 1440

typedef __attribute__((ext_vector_type(8))) short bf16x8v;
typedef __attribute__((ext_vector_type(4))) float f32x4v;

__device__ __forceinline__ float b2f(unsigned short u) {
  return __uint_as_float(((unsigned)u) << 16);
}
__device__ __forceinline__ unsigned short f2bu(float f) {
  __hip_bfloat16 h = __float2bfloat16(f);
  return *reinterpret_cast<unsigned short*>(&h);
}

// ---------------- weight conversion prekernel
__global__ void cvt_w(const float* __restrict__ Wq, const float* __restrict__ Wk,
                      const float* __restrict__ Wv, const float* __restrict__ Wqp,
                      const float* __restrict__ Wkp, const float* __restrict__ Wvp,
                      const float* __restrict__ Wo,
                      const float* __restrict__ w1, const float* __restrict__ w2,
                      const float* __restrict__ w3,
                      __hip_bfloat16* __restrict__ WBt, __hip_bfloat16* __restrict__ WoT,
                      __hip_bfloat16* __restrict__ W1T, __hip_bfloat16* __restrict__ W2T,
                      __hip_bfloat16* __restrict__ W3T)
{
  int idx = blockIdx.x*256 + threadIdx.x;
  if (idx < 2016*128) {
    int c = idx >> 7, k = idx & 127;
    float v;
    if      (c < 384)  v = Wq [k*384 + c];
    else if (c < 768)  v = Wk [k*384 + (c-384)];
    else if (c < 1152) v = Wv [k*384 + (c-768)];
    else if (c < 1440) v = Wqp[k*288 + (c-1152)];
    else if (c < 1728) v = Wkp[k*288 + (c-1440)];
    else               v = Wvp[k*288 + (c-1728)];
    WBt[idx] = __float2bfloat16(v);
    return;
  }
  int j = idx - 2016*128;
  if (j < 128*1440) {
    int c = j / 1440, k = j - c*1440;
    WoT[j] = __float2bfloat16(Wo[k*128 + c]);
    return;
  }
  int m = j - 128*1440;
  if (m < 3*16384) {
    int layer = m >> 14, cm = m & 16383;
    int c = cm >> 7, k = cm & 127;
    const float* w = (layer == 0) ? w1 : (layer == 1) ? w2 : w3;
    __hip_bfloat16* o = (layer == 0) ? W1T : (layer == 1) ? W2T : W3T;
    o[cm] = __float2bfloat16(w[k*128 + c]);
  }
}

// ---------------- MFMA projection; A staged from f32 x with inline bf16 cvt
__global__ __launch_bounds__(256) void proj_mfma(
    const float* __restrict__ x, const __hip_bfloat16* __restrict__ WBt,
    float* __restrict__ Pq, float* __restrict__ Pqp, float* __restrict__ Pkp,
    __hip_bfloat16* __restrict__ KE, __hip_bfloat16* __restrict__ VE)
{
  __shared__ short A_lds[64*136];
  __shared__ short B_lds[128*136];
  const int t = threadIdx.x;
  const int n0 = blockIdx.x * 64;
  const int c0 = blockIdx.y * 128;
  {
    int r = t >> 2, kc = (t & 3) * 32;
    int gr = n0 + r; if (gr >= NN) gr = NN-1;
    const float4* src = (const float4*)(x + (size_t)gr*128 + kc);
    unsigned* dstp = (unsigned*)&A_lds[r*136 + kc];
    #pragma unroll
    for (int j = 0; j < 8; j++) {
      float4 v = src[j];
      dstp[j*2+0] = (unsigned)f2bu(v.x) | ((unsigned)f2bu(v.y) << 16);
      dstp[j*2+1] = (unsigned)f2bu(v.z) | ((unsigned)f2bu(v.w) << 16);
    }
  }
  {
    int cI = t >> 1, ko = (t & 1) * 64;
    int gc = c0 + cI; if (gc > 2015) gc = 2015;
    const uint4* src = (const uint4*)(WBt + (size_t)gc*128 + ko);
    #pragma unroll
    for (int j = 0; j < 8; j++)
      *(uint4*)&B_lds[cI*136 + ko + j*8] = src[j];
  }
  __syncthreads();
  const int lane = t & 63, wid = t >> 6;
  const int wm = wid >> 1, wn = wid & 1;
  const int lrow = lane >> 4, lcol = lane & 15;
  f32x4v zero = {0.f, 0.f, 0.f, 0.f};
  f32x4v acc[2][4];
  #pragma unroll
  for (int i = 0; i < 2; i++)
    #pragma unroll
    for (int j = 0; j < 4; j++) acc[i][j] = zero;
  #pragma unroll
  for (int ks = 0; ks < 4; ks++) {
    int kb = ks*32 + lrow*8;
    bf16x8v a0 = *(const bf16x8v*)&A_lds[(wm*32 +      lcol)*136 + kb];
    bf16x8v a1 = *(const bf16x8v*)&A_lds[(wm*32 + 16 + lcol)*136 + kb];
    #pragma unroll
    for (int nt = 0; nt < 4; nt++) {
      bf16x8v b = *(const bf16x8v*)&B_lds[(wn*64 + nt*16 + lcol)*136 + kb];
      acc[0][nt] = __builtin_amdgcn_mfma_f32_16x16x32_bf16(a0, b, acc[0][nt], 0, 0, 0);
      acc[1][nt] = __builtin_amdgcn_mfma_f32_16x16x32_bf16(a1, b, acc[1][nt], 0, 0, 0);
    }
  }
  #pragma unroll
  for (int nt = 0; nt < 4; nt++) {
    int colb = c0 + wn*64 + nt*16;
    if (colb >= 2016) continue;
    int col = colb + lcol;
    #pragma unroll
    for (int mt = 0; mt < 2; mt++) {
      #pragma unroll
      for (int r = 0; r < 4; r++) {
        int grow = n0 + wm*32 + mt*16 + lrow*4 + r;
        if (grow >= NN) continue;
        float v = acc[mt][nt][r];
        if      (col < 384)  Pq[(size_t)grow*PQ_COLS + col] = v;
        else if (col < 768)  { int d = col-384; KE[(size_t)grow*KE_COLS + (d>>5)*64 + (d&31)] = __float2bfloat16(v); }
        else if (col < 1152) VE[(size_t)grow*VE_COLS + (col-768)] = __float2bfloat16(v);
        else if (col < 1440) Pqp[(size_t)grow*PQP_COLS + (col-1152)] = v;
        else if (col < 1728) Pkp[(size_t)grow*PKP_COLS + (col-1440)] = v;
        else                 VE[(size_t)grow*VE_COLS + 384 + (col-1728)] = __float2bfloat16(v);
      }
    }
  }
}

// ---------------- fused per-node prep (unchanged)
__global__ __launch_bounds__(256) void prep_node(
    const float* __restrict__ Pq, const float* __restrict__ Pqp, const float* __restrict__ Pkp,
    const float* __restrict__ R, const float* __restrict__ tr, const float* __restrict__ spc,
    __hip_bfloat16* __restrict__ QE, __hip_bfloat16* __restrict__ KE,
    __hip_bfloat16* __restrict__ VE)
{
  __shared__ float qpg[288];
  __shared__ float skk[12], cf[12];
  const int n = blockIdx.x, t = threadIdx.x;
  if (t < 12) { cf[t] = log1pf(expf(spc[t])) * (1.f/12.f); skk[t] = 0.f; }
  __syncthreads();
  const float* Rn = R + (size_t)n*9;
  const float r0=Rn[0],r1=Rn[1],r2=Rn[2],r3=Rn[3],r4=Rn[4],r5=Rn[5],r6=Rn[6],r7=Rn[7],r8=Rn[8];
  const float t0=tr[n*3],t1=tr[n*3+1],t2=tr[n*3+2];
  for (int task = t; task < 288; task += 256) {
    if (task < 96) {
      const float* p = Pqp + (size_t)n*PQP_COLS + task*3;
      float l0=p[0],l1=p[1],l2=p[2];
      qpg[task*3+0] = r0*l0+r1*l1+r2*l2+t0;
      qpg[task*3+1] = r3*l0+r4*l1+r5*l2+t1;
      qpg[task*3+2] = r6*l0+r7*l1+r8*l2+t2;
    } else if (task < 192) {
      int j = task-96, h = j>>3, jj = j&7;
      const float* p = Pkp + (size_t)n*PKP_COLS + h*24 + jj*3;
      float l0=p[0],l1=p[1],l2=p[2];
      __hip_bfloat16 b0=__float2bfloat16(r0*l0+r1*l1+r2*l2+t0);
      __hip_bfloat16 b1=__float2bfloat16(r3*l0+r4*l1+r5*l2+t1);
      __hip_bfloat16 b2=__float2bfloat16(r6*l0+r7*l1+r8*l2+t2);
      __hip_bfloat16* o = KE + (size_t)n*KE_COLS + h*64 + 32 + jj*3;
      o[0]=b0; o[1]=b1; o[2]=b2;
      float f0=__bfloat162float(b0), f1=__bfloat162float(b1), f2=__bfloat162float(b2);
      atomicAdd(&skk[h], f0*f0 + f1*f1 + f2*f2);
    } else {
      __hip_bfloat16* p = VE + (size_t)n*VE_COLS + 384 + (task-192)*3;
      float l0=__bfloat162float(p[0]), l1=__bfloat162float(p[1]), l2=__bfloat162float(p[2]);
      p[0] = __float2bfloat16(r0*l0+r1*l1+r2*l2+t0);
      p[1] = __float2bfloat16(r3*l0+r4*l1+r5*l2+t1);
      p[2] = __float2bfloat16(r6*l0+r7*l1+r8*l2+t2);
    }
  }
  __syncthreads();
  #pragma unroll
  for (int u = 0; u < 3; u++) {
    int s = t + 256*u;
    int h = s >> 6, i = s & 63;
    float val = 0.f;
    if (i < 32)      val = 0.1020620726f * Pq[(size_t)n*PQ_COLS + h*32 + i];
    else if (i < 56) val = 1.15470053838f * cf[h] * qpg[h*24 + (i-32)];
    else if (i == 58 || i == 59) val = 1.0f;
    QE[(size_t)n*QE_COLS + s] = __float2bfloat16(val);
  }
  if (t < 96) {
    int h = t >> 3, i = t & 7;
    float skkp = -0.57735026919f * cf[h] * skk[h];
    __hip_bfloat16 hi = __float2bfloat16(skkp);
    float res = skkp - __bfloat162float(hi);
    __hip_bfloat16 outv;
    if (i == 2)      outv = hi;
    else if (i == 3) outv = __float2bfloat16(res);
    else             outv = __float2bfloat16(0.0f);
    KE[(size_t)n*KE_COLS + h*64 + 56 + i] = outv;
  }
}

// ---------------- pair-logit panel + edge counting (fused)
__global__ __launch_bounds__(256) void pl_count(
    const float* __restrict__ z, const float* __restrict__ Wpair,
    const int* __restrict__ ei, float* __restrict__ PL, int* __restrict__ cnt)
{
  __shared__ float wp[384];
  const int t = threadIdx.x;
  for (int i = t; i < 384; i += 256) wp[i] = Wpair[i] * 0.57735026919f;
  __syncthreads();
  int e0 = blockIdx.x * 64;
  if (t < 64) {
    int e = e0 + t;
    if (e < EE) atomicAdd(&cnt[ei[e]], 1);
  }
  #pragma unroll
  for (int u = 0; u < 3; u++) {
    int idx = t + 256*u;
    int q = idx / 12, h = idx - 12*q;
    int e = e0 + q;
    if (q < 64 && e < EE) {
      const float* zr = z + (size_t)e*32;
      float s = 0.f;
      #pragma unroll
      for (int c = 0; c < 32; c++) s += zr[c] * wp[c*12 + h];
      PL[(size_t)e*12 + h] = s;
    }
  }
}

// ---------------- CSR build
__global__ __launch_bounds__(1024) void scan_csr(const int* __restrict__ cnt,
                                                 int* __restrict__ rowptr,
                                                 int* __restrict__ cursor)
{
  __shared__ int part[1024];
  int t = threadIdx.x;
  int base = t*20;
  int loc[20];
  int s = 0;
  #pragma unroll
  for (int i = 0; i < 20; i++) {
    int idx = base + i;
    int cc = (idx < NN) ? cnt[idx] : 0;
    loc[i] = s; s += cc;
  }
  part[t] = s;
  __syncthreads();
  for (int off = 1; off < 1024; off <<= 1) {
    int v = (t >= off) ? part[t-off] : 0;
    __syncthreads();
    part[t] += v;
    __syncthreads();
  }
  int pre = (t == 0) ? 0 : part[t-1];
  #pragma unroll
  for (int i = 0; i < 20; i++) {
    int idx = base + i;
    if (idx < NN) { rowptr[idx] = pre + loc[i]; cursor[idx] = pre + loc[i]; }
  }
  if (t == 1023) rowptr[NN] = part[1023];
}

__global__ void fill_csr(const int* __restrict__ ei, int* __restrict__ cursor,
                         int* __restrict__ eidx, int* __restrict__ dstE)
{
  int e = blockIdx.x*256 + threadIdx.x;
  if (e >= EE) return;
  int pos = atomicAdd(&cursor[ei[e]], 1);
  eidx[pos] = e;
  dstE[pos] = ei[EE + e];
}

__device__ __forceinline__ float dot8(const float* qr, uint4 v) {
  float s;
  s  = qr[0]*b2f((unsigned short)(v.x & 0xffffu));
  s += qr[1]*b2f((unsigned short)(v.x >> 16));
  s += qr[2]*b2f((unsigned short)(v.y & 0xffffu));
  s += qr[3]*b2f((unsigned short)(v.y >> 16));
  s += qr[4]*b2f((unsigned short)(v.z & 0xffffu));
  s += qr[5]*b2f((unsigned short)(v.z >> 16));
  s += qr[6]*b2f((unsigned short)(v.w & 0xffffu));
  s += qr[7]*b2f((unsigned short)(v.w >> 16));
  return s;
}

// ---------------- wave-per-node fused attention (r13-proven single-edge body)
__global__ __launch_bounds__(256) void attn_wave(
    const __hip_bfloat16* __restrict__ QE,
    const __hip_bfloat16* __restrict__ KE,
    const __hip_bfloat16* __restrict__ VE,
    const float* __restrict__ z, const float* __restrict__ PL,
    const int* __restrict__ rowptr, const int* __restrict__ eidx,
    const int* __restrict__ dstE,
    const float* __restrict__ R, const float* __restrict__ tr,
    __hip_bfloat16* __restrict__ featB)
{
  __shared__ float sAgg[4][288];
  const int wid = threadIdx.x >> 6, lane = threadIdx.x & 63;
  const int n = blockIdx.x*4 + wid;

  float q0[8], q1[8];
  {
    const uint4* qrow = (const uint4*)(QE + (size_t)n*QE_COLS);
    uint4 Q0 = qrow[lane];
    q0[0]=b2f((unsigned short)(Q0.x&0xffffu)); q0[1]=b2f((unsigned short)(Q0.x>>16));
    q0[2]=b2f((unsigned short)(Q0.y&0xffffu)); q0[3]=b2f((unsigned short)(Q0.y>>16));
    q0[4]=b2f((unsigned short)(Q0.z&0xffffu)); q0[5]=b2f((unsigned short)(Q0.z>>16));
    q0[6]=b2f((unsigned short)(Q0.w&0xffffu)); q0[7]=b2f((unsigned short)(Q0.w>>16));
    if (lane < 32) {
      uint4 Q1 = qrow[64 + lane];
      q1[0]=b2f((unsigned short)(Q1.x&0xffffu)); q1[1]=b2f((unsigned short)(Q1.x>>16));
      q1[2]=b2f((unsigned short)(Q1.y&0xffffu)); q1[3]=b2f((unsigned short)(Q1.y>>16));
      q1[4]=b2f((unsigned short)(Q1.z&0xffffu)); q1[5]=b2f((unsigned short)(Q1.z>>16));
      q1[6]=b2f((unsigned short)(Q1.w&0xffffu)); q1[7]=b2f((unsigned short)(Q1.w>>16));
    } else {
      #pragma unroll
      for (int j = 0; j < 8; j++) q1[j] = 0.f;
    }
  }

  const int myh0 = (lane < 48) ? (lane >> 2) : ((8*lane - 384) / 24);
  const int myh1 = (128 + 8*lane) / 24;

  float mreg = -1e30f, sreg = 0.f;
  float accV0[8] = {}, accV1[8] = {}, accZ[12] = {};

  const int beg = rowptr[n], end = rowptr[n+1];
  for (int c0 = beg; c0 < end; c0 += 64) {
    const int cn = min(64, end - c0);
    int eL = (lane < cn) ? eidx[c0 + lane] : 0;
    int dL = (lane < cn) ? dstE[c0 + lane] : 0;
    for (int j = 0; j < cn; j++) {
      const int e   = __shfl(eL, j);
      const int dst = __shfl(dL, j);
      const uint4* ke = (const uint4*)(KE + (size_t)dst*KE_COLS);
      uint4 K0 = ke[lane];
      uint4 K1 = make_uint4(0,0,0,0);
      if (lane < 32) K1 = ke[64 + lane];
      const uint4* ve = (const uint4*)(VE + (size_t)dst*VE_COLS);
      uint4 V0 = ve[lane];
      uint4 V1 = make_uint4(0,0,0,0);
      if (lane < 20) V1 = ve[64 + lane];
      float zc = (lane < 32) ? z[(size_t)e*32 + lane] : 0.f;
      float pl = (lane < 12) ? PL[(size_t)e*12 + lane] : 0.f;
      float p0 = dot8(q0, K0);
      p0 += __shfl_xor(p0, 1); p0 += __shfl_xor(p0, 2); p0 += __shfl_xor(p0, 4);
      float p1 = dot8(q1, K1);
      p1 += __shfl_xor(p1, 1); p1 += __shfl_xor(p1, 2); p1 += __shfl_xor(p1, 4);
      float pa = __shfl(p0, (lane & 7) * 8);
      float pb = __shfl(p1, (lane & 3) * 8);
      float lg = ((lane < 8) ? pa : pb) + pl;
      float mn = fmaxf(mreg, lg);
      unsigned long long chg = __ballot(mn > mreg) & 0xFFFull;
      float w = expf(lg - mn);
      float r = expf(mreg - mn);
      mreg = mn;
      sreg = sreg * r + w;
      if (chg) {
        float rv0 = __shfl(r, myh0);
        #pragma unroll
        for (int q2 = 0; q2 < 8; q2++) accV0[q2] *= rv0;
        float rv1 = __shfl(r, myh1);
        if (lane < 20) {
          #pragma unroll
          for (int q2 = 0; q2 < 8; q2++) accV1[q2] *= rv1;
        }
        #pragma unroll
        for (int h = 0; h < 12; h++) accZ[h] *= __shfl(r, h);
      }
      float wv0 = __shfl(w, myh0);
      accV0[0] += wv0 * b2f((unsigned short)(V0.x & 0xffffu));
      accV0[1] += wv0 * b2f((unsigned short)(V0.x >> 16));
      accV0[2] += wv0 * b2f((unsigned short)(V0.y & 0xffffu));
      accV0[3] += wv0 * b2f((unsigned short)(V0.y >> 16));
      accV0[4] += wv0 * b2f((unsigned short)(V0.z & 0xffffu));
      accV0[5] += wv0 * b2f((unsigned short)(V0.z >> 16));
      accV0[6] += wv0 * b2f((unsigned short)(V0.w & 0xffffu));
      accV0[7] += wv0 * b2f((unsigned short)(V0.w >> 16));
      float wv1 = __shfl(w, myh1);
      if (lane < 20) {
        accV1[0] += wv1 * b2f((unsigned short)(V1.x & 0xffffu));
        accV1[1] += wv1 * b2f((unsigned short)(V1.x >> 16));
        accV1[2] += wv1 * b2f((unsigned short)(V1.y & 0xffffu));
        accV1[3] += wv1 * b2f((unsigned short)(V1.y >> 16));
        accV1[4] += wv1 * b2f((unsigned short)(V1.z & 0xffffu));
        accV1[5] += wv1 * b2f((unsigned short)(V1.z >> 16));
        accV1[6] += wv1 * b2f((unsigned short)(V1.w & 0xffffu));
        accV1[7] += wv1 * b2f((unsigned short)(V1.w >> 16));
      }
      #pragma unroll
      for (int h = 0; h < 12; h++) accZ[h] += __shfl(w, h) * zc;
    }
  }

  float inv = 0.f;
  if (lane < 12) inv = (sreg > 0.f) ? 1.f/sreg : 0.f;
  __hip_bfloat16* fr = featB + (size_t)n*FCOLS;
  #pragma unroll
  for (int h = 0; h < 12; h++) {
    float iv = __shfl(inv, h);
    if (lane < 32) fr[h*32 + lane] = __float2bfloat16(accZ[h] * iv);
  }
  float iv0 = __shfl(inv, myh0);
  if (lane < 48) {
    uint4 P;
    P.x = (unsigned)f2bu(accV0[0]*iv0) | ((unsigned)f2bu(accV0[1]*iv0) << 16);
    P.y = (unsigned)f2bu(accV0[2]*iv0) | ((unsigned)f2bu(accV0[3]*iv0) << 16);
    P.z = (unsigned)f2bu(accV0[4]*iv0) | ((unsigned)f2bu(accV0[5]*iv0) << 16);
    P.w = (unsigned)f2bu(accV0[6]*iv0) | ((unsigned)f2bu(accV0[7]*iv0) << 16);
    *(uint4*)(fr + 384 + lane*8) = P;
  } else {
    #pragma unroll
    for (int j2 = 0; j2 < 8; j2++) sAgg[wid][(lane-48)*8 + j2] = accV0[j2]*iv0;
  }
  float iv1 = __shfl(inv, myh1);
  if (lane < 20) {
    #pragma unroll
    for (int j2 = 0; j2 < 8; j2++) sAgg[wid][128 + lane*8 + j2] = accV1[j2]*iv1;
  }
  __syncthreads();
  {
    const float* Rn = R + (size_t)n*9;
    float t0 = tr[n*3], t1 = tr[n*3+1], t2 = tr[n*3+2];
    #pragma unroll
    for (int pp = 0; pp < 2; pp++) {
      int pt = lane + pp*64;
      if (pt < 96) {
        float d0 = sAgg[wid][pt*3+0] - t0;
        float d1 = sAgg[wid][pt*3+1] - t1;
        float d2 = sAgg[wid][pt*3+2] - t2;
        float l0 = Rn[0]*d0 + Rn[3]*d1 + Rn[6]*d2;
        float l1 = Rn[1]*d0 + Rn[4]*d1 + Rn[7]*d2;
        float l2 = Rn[2]*d0 + Rn[5]*d1 + Rn[8]*d2;
        float nr = sqrtf(l0*l0 + l1*l1 + l2*l2);
        float ivn = 1.f / fmaxf(nr, 1e-8f);
        fr[768 + pt*3+0] = __float2bfloat16(l0);
        fr[768 + pt*3+1] = __float2bfloat16(l1);
        fr[768 + pt*3+2] = __float2bfloat16(l2);
        fr[1056 + pt]    = __float2bfloat16(nr);
        fr[1152 + pt*3+0] = __float2bfloat16(l0*ivn);
        fr[1152 + pt*3+1] = __float2bfloat16(l1*ivn);
        fr[1152 + pt*3+2] = __float2bfloat16(l2*ivn);
      }
    }
  }
}

// ---------------- fused Wo GEMM + LN1 + MLP(MFMA) + residual + LN2 -> out
__global__ __launch_bounds__(256) void wo_mlp(
    const __hip_bfloat16* __restrict__ featB, const __hip_bfloat16* __restrict__ WoT,
    const float* __restrict__ bo, const float* __restrict__ x,
    const __hip_bfloat16* __restrict__ W1T, const float* __restrict__ bb1,
    const __hip_bfloat16* __restrict__ W2T, const float* __restrict__ bb2,
    const __hip_bfloat16* __restrict__ W3T, const float* __restrict__ bb3,
    const float* __restrict__ g1, const float* __restrict__ b1v,
    const float* __restrict__ g2, const float* __restrict__ b2v,
    float* __restrict__ out)
{
  __shared__ float4 arenaV[3200];   // 51200 bytes, 16B-aligned
  __shared__ float mu_s[64], rs_s[64];
  char* arena  = (char*)arenaV;
  short* A_lds = (short*)arena;
  short* B_lds = (short*)(arena + 13312);
  float* hs    = (float*)arena;
  short* actB  = (short*)(arena + 33792);

  const int t = threadIdx.x;
  const int n0 = blockIdx.x * 64;
  const int lane = t & 63, wid = t >> 6;
  const int wm = wid >> 1, wn = wid & 1;
  const int lrow = lane >> 4, lcol = lane & 15;
  f32x4v zero = {0.f, 0.f, 0.f, 0.f};

  f32x4v acc[2][4];
  #pragma unroll
  for (int i = 0; i < 2; i++)
    #pragma unroll
    for (int j = 0; j < 4; j++) acc[i][j] = zero;
  for (int k0 = 0; k0 < 1440; k0 += 96) {
    __syncthreads();
    {
      int r = t >> 2, kc = (t & 3) * 24;
      int gr = n0 + r; if (gr >= NN) gr = NN-1;
      const uint4* src = (const uint4*)(featB + (size_t)gr*FCOLS + k0 + kc);
      uint4 v0 = src[0], v1 = src[1], v2 = src[2];
      *(uint4*)&A_lds[r*104 + kc +  0] = v0;
      *(uint4*)&A_lds[r*104 + kc +  8] = v1;
      *(uint4*)&A_lds[r*104 + kc + 16] = v2;
    }
    {
      int cI = t >> 1, ko = (t & 1) * 48;
      const uint4* src = (const uint4*)(WoT + (size_t)cI*1440 + k0 + ko);
      #pragma unroll
      for (int j = 0; j < 6; j++)
        *(uint4*)&B_lds[cI*104 + ko + j*8] = src[j];
    }
    __syncthreads();
    #pragma unroll
    for (int ks = 0; ks < 3; ks++) {
      int kb = ks*32 + lrow*8;
      bf16x8v a0 = *(const bf16x8v*)&A_lds[(wm*32 +      lcol)*104 + kb];
      bf16x8v a1 = *(const bf16x8v*)&A_lds[(wm*32 + 16 + lcol)*104 + kb];
      #pragma unroll
      for (int nt = 0; nt < 4; nt++) {
        bf16x8v b = *(const bf16x8v*)&B_lds[(wn*64 + nt*16 + lcol)*104 + kb];
        acc[0][nt] = __builtin_amdgcn_mfma_f32_16x16x32_bf16(a0, b, acc[0][nt], 0, 0, 0);
        acc[1][nt] = __builtin_amdgcn_mfma_f32_16x16x32_bf16(a1, b, acc[1][nt], 0, 0, 0);
      }
    }
  }
  __syncthreads();
  #pragma unroll
  for (int nt = 0; nt < 4; nt++) {
    int col = wn*64 + nt*16 + lcol;
    float bv = bo[col];
    #pragma unroll
    for (int mt = 0; mt < 2; mt++) {
      #pragma unroll
      for (int r = 0; r < 4; r++) {
        int row = wm*32 + mt*16 + lrow*4 + r;
        int gr = n0 + row; if (gr >= NN) gr = NN-1;
        hs[row*132 + col] = acc[mt][nt][r] + bv + x[(size_t)gr*128 + col];
      }
    }
  }
  __syncthreads();
  for (int q = 0; q < 16; q++) {
    int r = wid*16 + q;
    float v0 = hs[r*132 + lane], v1 = hs[r*132 + lane + 64];
    float s = v0 + v1, ss = v0*v0 + v1*v1;
    #pragma unroll
    for (int m2 = 32; m2 >= 1; m2 >>= 1) { s += __shfl_xor(s, m2); ss += __shfl_xor(ss, m2); }
    if (lane == 0) { float mu = s*(1.f/128.f); mu_s[r] = mu; rs_s[r] = rsqrtf(ss*(1.f/128.f) - mu*mu + 1e-5f); }
  }
  __syncthreads();
  for (int e = t; e < 8192; e += 256) {
    int r = e >> 7, c = e & 127;
    float v = (hs[r*132 + c] - mu_s[r]) * rs_s[r] * g1[c] + b1v[c];
    hs[r*132 + c] = v;
    actB[r*136 + c] = (short)f2bu(v);
  }
  __syncthreads();

#define MLP_MFMA_LAYER(WT, BIAS, IS_LAST)                                       \
  {                                                                             \
    f32x4v acc2[2][4];                                                          \
    _Pragma("unroll")                                                           \
    for (int i = 0; i < 2; i++)                                                 \
      _Pragma("unroll")                                                         \
      for (int j = 0; j < 4; j++) acc2[i][j] = zero;                            \
    _Pragma("unroll")                                                           \
    for (int ks = 0; ks < 4; ks++) {                                            \
      int kb = ks*32 + lrow*8;                                                  \
      bf16x8v a0 = *(const bf16x8v*)&actB[(wm*32 +      lcol)*136 + kb];        \
      bf16x8v a1 = *(const bf16x8v*)&actB[(wm*32 + 16 + lcol)*136 + kb];        \
      _Pragma("unroll")                                                         \
      for (int nt = 0; nt < 4; nt++) {                                          \
        int col = wn*64 + nt*16 + lcol;                                         \
        bf16x8v b = *(const bf16x8v*)(WT + (size_t)col*128 + kb);               \
        acc2[0][nt] = __builtin_amdgcn_mfma_f32_16x16x32_bf16(a0, b, acc2[0][nt], 0, 0, 0); \
        acc2[1][nt] = __builtin_amdgcn_mfma_f32_16x16x32_bf16(a1, b, acc2[1][nt], 0, 0, 0); \
      }                                                                         \
    }                                                                           \
    __syncthreads();                                                            \
    _Pragma("unroll")                                                           \
    for (int nt = 0; nt < 4; nt++) {                                            \
      int col = wn*64 + nt*16 + lcol;                                           \
      float bv = BIAS[col];                                                     \
      _Pragma("unroll")                                                         \
      for (int mt = 0; mt < 2; mt++) {                                          \
        _Pragma("unroll")                                                       \
        for (int r = 0; r < 4; r++) {                                           \
          int row = wm*32 + mt*16 + lrow*4 + r;                                 \
          float v = acc2[mt][nt][r] + bv;                                       \
          if (IS_LAST) hs[row*132 + col] += v;                                  \
          else         actB[row*136 + col] = (short)f2bu(fmaxf(v, 0.f));        \
        }                                                                       \
      }                                                                         \
    }                                                                           \
    __syncthreads();                                                            \
  }

  MLP_MFMA_LAYER(W1T, bb1, 0)
  MLP_MFMA_LAYER(W2T, bb2, 0)
  MLP_MFMA_LAYER(W3T, bb3, 1)
#undef MLP_MFMA_LAYER

  for (int q = 0; q < 16; q++) {
    int r = wid*16 + q;
    float v0 = hs[r*132 + lane], v1 = hs[r*132 + lane + 64];
    float s = v0 + v1, ss = v0*v0 + v1*v1;
    #pragma unroll
    for (int m2 = 32; m2 >= 1; m2 >>= 1) { s += __shfl_xor(s, m2); ss += __shfl_xor(ss, m2); }
    if (lane == 0) { float mu = s*(1.f/128.f); mu_s[r] = mu; rs_s[r] = rsqrtf(ss*(1.f/128.f) - mu*mu + 1e-5f); }
  }
  __syncthreads();
  for (int e = t; e < 8192; e += 256) {
    int r = e >> 7, c = e & 127;
    int gr = n0 + r;
    if (gr < NN)
      out[(size_t)gr*128 + c] = (hs[r*132 + c] - mu_s[r]) * rs_s[r] * g2[c] + b2v[c];
  }
}

__global__ void diag_ws(float* out, float v)
{
  if (blockIdx.x == 0 && threadIdx.x == 0) out[0] = v;
}

// ---------------- host side ----------------
static inline size_t alup(size_t v) { return (v + 255) & ~(size_t)255; }

extern "C" void kernel_launch(void* const* d_in, const int* in_sizes, int n_in,
                              void* d_out, int out_size, void* d_ws, size_t ws_size,
                              hipStream_t stream)
{
  const float* R     = (const float*)d_in[0];
  const float* tr    = (const float*)d_in[1];
  const float* x     = (const float*)d_in[2];
  const float* z     = (const float*)d_in[3];
  const int*   ei    = (const int*)  d_in[4];
  const float* Wq    = (const float*)d_in[5];
  const float* Wk    = (const float*)d_in[6];
  const float* Wv    = (const float*)d_in[7];
  const float* Wpair = (const float*)d_in[8];
  const float* spc   = (const float*)d_in[9];
  const float* Wqp   = (const float*)d_in[10];
  const float* Wkp   = (const float*)d_in[11];
  const float* Wvp   = (const float*)d_in[12];
  const float* Wo    = (const float*)d_in[13];
  const float* bo    = (const float*)d_in[14];
  const float* g1    = (const float*)d_in[15];
  const float* b1v   = (const float*)d_in[16];
  const float* w1    = (const float*)d_in[17];
  const float* bb1   = (const float*)d_in[18];
  const float* w2    = (const float*)d_in[19];
  const float* bb2   = (const float*)d_in[20];
  const float* w3    = (const float*)d_in[21];
  const float* bb3   = (const float*)d_in[22];
  const float* g2    = (const float*)d_in[23];
  const float* b2v   = (const float*)d_in[24];
  float* out = (float*)d_out;
  char* ws = (char*)d_ws;

  size_t pq_b  = alup((size_t)NN*PQ_COLS*4);
  size_t pqp_b = alup((size_t)NN*PQP_COLS*4);
  size_t pkp_b = alup((size_t)NN*PKP_COLS*4);
  size_t region = pq_b + pqp_b + pkp_b;
  size_t fb_b = alup((size_t)NN*FCOLS*2);
  size_t pl_b = alup((size_t)EE*12*4);
  if (fb_b + pl_b > region) region = fb_b + pl_b;

  float* Pq  = (float*)ws;
  float* Pqp = (float*)(ws + pq_b);
  float* Pkp = (float*)(ws + pq_b + pqp_b);
  __hip_bfloat16* featB = (__hip_bfloat16*)ws;
  float* PL  = (float*)(ws + fb_b);

  size_t off = region;
  __hip_bfloat16* QE = (__hip_bfloat16*)(ws + off); off += alup((size_t)NN*QE_COLS*2);
  __hip_bfloat16* VE = (__hip_bfloat16*)(ws + off); off += alup((size_t)NN*VE_COLS*2);
  __hip_bfloat16* KE = (__hip_bfloat16*)(ws + off); off += alup((size_t)NN*KE_COLS*2);
  int* cnt = (int*)(ws + off);       off += alup((size_t)NN*4);
  int* rowptr = (int*)(ws + off);    off += alup((size_t)(NN+1)*4);
  int* cursor = (int*)(ws + off);    off += alup((size_t)NN*4);
  int* eidx = (int*)(ws + off);      off += alup((size_t)EE*4);
  int* dstE = (int*)(ws + off);      off += alup((size_t)EE*4);
  __hip_bfloat16* WBt = (__hip_bfloat16*)(ws + off); off += alup((size_t)2016*128*2);
  __hip_bfloat16* WoT = (__hip_bfloat16*)(ws + off); off += alup((size_t)128*1440*2);
  __hip_bfloat16* W1T = (__hip_bfloat16*)(ws + off); off += alup((size_t)128*128*2);
  __hip_bfloat16* W2T = (__hip_bfloat16*)(ws + off); off += alup((size_t)128*128*2);
  __hip_bfloat16* W3T = (__hip_bfloat16*)(ws + off); off += alup((size_t)128*128*2);

  if (ws_size < off) {
    diag_ws<<<1, 64, 0, stream>>>(out, (float)((double)ws_size / (1024.0*1024.0)));
    return;
  }

  hipMemsetAsync(cnt, 0, (size_t)NN*4, stream);

  cvt_w<<<(2016*128 + 128*1440 + 3*16384 + 255)/256, 256, 0, stream>>>(
      Wq, Wk, Wv, Wqp, Wkp, Wvp, Wo, w1, w2, w3, WBt, WoT, W1T, W2T, W3T);
  proj_mfma<<<dim3((NN + 63)/64, 16), 256, 0, stream>>>(x, WBt, Pq, Pqp, Pkp, KE, VE);
  prep_node<<<NN, 256, 0, stream>>>(Pq, Pqp, Pkp, R, tr, spc, QE, KE, VE);
  pl_count<<<(EE + 63)/64, 256, 0, stream>>>(z, Wpair, ei, PL, cnt);
  scan_csr<<<1, 1024, 0, stream>>>(cnt, rowptr, cursor);
  fill_csr<<<EE/256, 256, 0, stream>>>(ei, cursor, eidx, dstE);
  attn_wave<<<NN/4, 256, 0, stream>>>(QE, KE, VE, z, PL, rowptr, eidx, dstE, R, tr, featB);
  wo_mlp<<<(NN + 63)/64, 256, 0, stream>>>(featB, WoT, bo, x,
                                           W1T, bb1, W2T, bb2, W3T, bb3,
                                           g1, b1v, g2, b2v, out);
}

// Round 16
// 394.028 us; speedup vs baseline: 1.0387x; 1.0387x over previous
//
#include <hip/hip_runtime.h>
#include <hip/hip_bf16.h>
#include <math.h>

#define NN 20000
#define EE 320000
#define PQP_COLS 288
#define PKP_COLS 288
#define QE_COLS  768
#define VE_COLS  672
#define KE_COLS  768
#define FCOLS 1440

typedef __attribute__((ext_vector_type(8))) short bf16x8v;
typedef __attribute__((ext_vector_type(4))) float f32x4v;

__device__ __forceinline__ float b2f(unsigned short u) {
  return __uint_as_float(((unsigned)u) << 16);
}
__device__ __forceinline__ unsigned short f2bu(float f) {
  __hip_bfloat16 h = __float2bfloat16(f);
  return *reinterpret_cast<unsigned short*>(&h);
}

// ---------------- weight conversion prekernel
__global__ void cvt_w(const float* __restrict__ Wq, const float* __restrict__ Wk,
                      const float* __restrict__ Wv, const float* __restrict__ Wqp,
                      const float* __restrict__ Wkp, const float* __restrict__ Wvp,
                      const float* __restrict__ Wo,
                      const float* __restrict__ w1, const float* __restrict__ w2,
                      const float* __restrict__ w3,
                      __hip_bfloat16* __restrict__ WBt, __hip_bfloat16* __restrict__ WoT,
                      __hip_bfloat16* __restrict__ W1T, __hip_bfloat16* __restrict__ W2T,
                      __hip_bfloat16* __restrict__ W3T)
{
  int idx = blockIdx.x*256 + threadIdx.x;
  if (idx < 2016*128) {
    int c = idx >> 7, k = idx & 127;
    float v;
    if      (c < 384)  v = Wq [k*384 + c];
    else if (c < 768)  v = Wk [k*384 + (c-384)];
    else if (c < 1152) v = Wv [k*384 + (c-768)];
    else if (c < 1440) v = Wqp[k*288 + (c-1152)];
    else if (c < 1728) v = Wkp[k*288 + (c-1440)];
    else               v = Wvp[k*288 + (c-1728)];
    WBt[idx] = __float2bfloat16(v);
    return;
  }
  int j = idx - 2016*128;
  if (j < 128*1440) {
    int c = j / 1440, k = j - c*1440;
    WoT[j] = __float2bfloat16(Wo[k*128 + c]);
    return;
  }
  int m = j - 128*1440;
  if (m < 3*16384) {
    int layer = m >> 14, cm = m & 16383;
    int c = cm >> 7, k = cm & 127;
    const float* w = (layer == 0) ? w1 : (layer == 1) ? w2 : w3;
    __hip_bfloat16* o = (layer == 0) ? W1T : (layer == 1) ? W2T : W3T;
    o[cm] = __float2bfloat16(w[k*128 + c]);
  }
}

// ---------------- MFMA projection; A staged once, 4 column-tiles per block.
// q columns are written DIRECTLY into QE (pre-scaled bf16) - Pq panel eliminated.
__global__ __launch_bounds__(256) void proj_mfma(
    const float* __restrict__ x, const __hip_bfloat16* __restrict__ WBt,
    float* __restrict__ Pqp, float* __restrict__ Pkp,
    __hip_bfloat16* __restrict__ QE, __hip_bfloat16* __restrict__ KE,
    __hip_bfloat16* __restrict__ VE)
{
  __shared__ short A_lds[64*136];
  __shared__ short B_lds[128*136];
  const int t = threadIdx.x;
  const int n0 = blockIdx.x * 64;
  const int lane = t & 63, wwid = t >> 6;
  const int wm = wwid >> 1, wn = wwid & 1;
  const int lrow = lane >> 4, lcol = lane & 15;
  f32x4v zero = {0.f, 0.f, 0.f, 0.f};

  // stage A once (64 rows x 128 k, f32 -> bf16 inline)
  {
    int r = t >> 2, kc = (t & 3) * 32;
    int gr = n0 + r; if (gr >= NN) gr = NN-1;
    const float4* src = (const float4*)(x + (size_t)gr*128 + kc);
    unsigned* dstp = (unsigned*)&A_lds[r*136 + kc];
    #pragma unroll
    for (int j = 0; j < 8; j++) {
      float4 v = src[j];
      dstp[j*2+0] = (unsigned)f2bu(v.x) | ((unsigned)f2bu(v.y) << 16);
      dstp[j*2+1] = (unsigned)f2bu(v.z) | ((unsigned)f2bu(v.w) << 16);
    }
  }

  for (int tile = 0; tile < 4; tile++) {
    const int c0 = blockIdx.y * 512 + tile * 128;
    __syncthreads();   // A ready (tile 0) / previous tile's MFMA reads done
    {
      int cI = t >> 1, ko = (t & 1) * 64;
      int gc = c0 + cI; if (gc > 2015) gc = 2015;
      const uint4* src = (const uint4*)(WBt + (size_t)gc*128 + ko);
      #pragma unroll
      for (int j = 0; j < 8; j++)
        *(uint4*)&B_lds[cI*136 + ko + j*8] = src[j];
    }
    __syncthreads();
    f32x4v acc[2][4];
    #pragma unroll
    for (int i = 0; i < 2; i++)
      #pragma unroll
      for (int j = 0; j < 4; j++) acc[i][j] = zero;
    #pragma unroll
    for (int ks = 0; ks < 4; ks++) {
      int kb = ks*32 + lrow*8;
      bf16x8v a0 = *(const bf16x8v*)&A_lds[(wm*32 +      lcol)*136 + kb];
      bf16x8v a1 = *(const bf16x8v*)&A_lds[(wm*32 + 16 + lcol)*136 + kb];
      #pragma unroll
      for (int nt = 0; nt < 4; nt++) {
        bf16x8v b = *(const bf16x8v*)&B_lds[(wn*64 + nt*16 + lcol)*136 + kb];
        acc[0][nt] = __builtin_amdgcn_mfma_f32_16x16x32_bf16(a0, b, acc[0][nt], 0, 0, 0);
        acc[1][nt] = __builtin_amdgcn_mfma_f32_16x16x32_bf16(a1, b, acc[1][nt], 0, 0, 0);
      }
    }
    #pragma unroll
    for (int nt = 0; nt < 4; nt++) {
      int colb = c0 + wn*64 + nt*16;
      if (colb >= 2016) continue;
      int col = colb + lcol;
      #pragma unroll
      for (int mt = 0; mt < 2; mt++) {
        #pragma unroll
        for (int r = 0; r < 4; r++) {
          int grow = n0 + wm*32 + mt*16 + lrow*4 + r;
          if (grow >= NN) continue;
          float v = acc[mt][nt][r];
          if      (col < 384)  QE[(size_t)grow*QE_COLS + (col>>5)*64 + (col&31)] = __float2bfloat16(0.1020620726f * v);
          else if (col < 768)  { int d = col-384; KE[(size_t)grow*KE_COLS + (d>>5)*64 + (d&31)] = __float2bfloat16(v); }
          else if (col < 1152) VE[(size_t)grow*VE_COLS + (col-768)] = __float2bfloat16(v);
          else if (col < 1440) Pqp[(size_t)grow*PQP_COLS + (col-1152)] = v;
          else if (col < 1728) Pkp[(size_t)grow*PKP_COLS + (col-1440)] = v;
          else                 VE[(size_t)grow*VE_COLS + 384 + (col-1728)] = __float2bfloat16(v);
        }
      }
    }
  }
}

// ---------------- fused per-node prep (q slots already in QE; fills the rest)
__global__ __launch_bounds__(256) void prep_node(
    const float* __restrict__ Pqp, const float* __restrict__ Pkp,
    const float* __restrict__ R, const float* __restrict__ tr, const float* __restrict__ spc,
    __hip_bfloat16* __restrict__ QE, __hip_bfloat16* __restrict__ KE,
    __hip_bfloat16* __restrict__ VE)
{
  __shared__ float qpg[288];
  __shared__ float skk[12], cf[12];
  const int n = blockIdx.x, t = threadIdx.x;
  if (t < 12) { cf[t] = log1pf(expf(spc[t])) * (1.f/12.f); skk[t] = 0.f; }
  __syncthreads();
  const float* Rn = R + (size_t)n*9;
  const float r0=Rn[0],r1=Rn[1],r2=Rn[2],r3=Rn[3],r4=Rn[4],r5=Rn[5],r6=Rn[6],r7=Rn[7],r8=Rn[8];
  const float t0=tr[n*3],t1=tr[n*3+1],t2=tr[n*3+2];
  for (int task = t; task < 288; task += 256) {
    if (task < 96) {
      const float* p = Pqp + (size_t)n*PQP_COLS + task*3;
      float l0=p[0],l1=p[1],l2=p[2];
      qpg[task*3+0] = r0*l0+r1*l1+r2*l2+t0;
      qpg[task*3+1] = r3*l0+r4*l1+r5*l2+t1;
      qpg[task*3+2] = r6*l0+r7*l1+r8*l2+t2;
    } else if (task < 192) {
      int j = task-96, h = j>>3, jj = j&7;
      const float* p = Pkp + (size_t)n*PKP_COLS + h*24 + jj*3;
      float l0=p[0],l1=p[1],l2=p[2];
      __hip_bfloat16 b0=__float2bfloat16(r0*l0+r1*l1+r2*l2+t0);
      __hip_bfloat16 b1=__float2bfloat16(r3*l0+r4*l1+r5*l2+t1);
      __hip_bfloat16 b2=__float2bfloat16(r6*l0+r7*l1+r8*l2+t2);
      __hip_bfloat16* o = KE + (size_t)n*KE_COLS + h*64 + 32 + jj*3;
      o[0]=b0; o[1]=b1; o[2]=b2;
      float f0=__bfloat162float(b0), f1=__bfloat162float(b1), f2=__bfloat162float(b2);
      atomicAdd(&skk[h], f0*f0 + f1*f1 + f2*f2);
    } else {
      __hip_bfloat16* p = VE + (size_t)n*VE_COLS + 384 + (task-192)*3;
      float l0=__bfloat162float(p[0]), l1=__bfloat162float(p[1]), l2=__bfloat162float(p[2]);
      p[0] = __float2bfloat16(r0*l0+r1*l1+r2*l2+t0);
      p[1] = __float2bfloat16(r3*l0+r4*l1+r5*l2+t1);
      p[2] = __float2bfloat16(r6*l0+r7*l1+r8*l2+t2);
    }
  }
  __syncthreads();
  #pragma unroll
  for (int u = 0; u < 3; u++) {
    int s = t + 256*u;
    int h = s >> 6, i = s & 63;
    if (i < 32) continue;                 // q slots written by proj_mfma
    float val = 0.f;
    if (i < 56)                  val = 1.15470053838f * cf[h] * qpg[h*24 + (i-32)];
    else if (i == 58 || i == 59) val = 1.0f;
    QE[(size_t)n*QE_COLS + s] = __float2bfloat16(val);
  }
  if (t < 96) {
    int h = t >> 3, i = t & 7;
    float skkp = -0.57735026919f * cf[h] * skk[h];
    __hip_bfloat16 hi = __float2bfloat16(skkp);
    float res = skkp - __bfloat162float(hi);
    __hip_bfloat16 outv;
    if (i == 2)      outv = hi;
    else if (i == 3) outv = __float2bfloat16(res);
    else             outv = __float2bfloat16(0.0f);
    KE[(size_t)n*KE_COLS + h*64 + 56 + i] = outv;
  }
}

// ---------------- pair-logit panel + edge counting (fused)
__global__ __launch_bounds__(256) void pl_count(
    const float* __restrict__ z, const float* __restrict__ Wpair,
    const int* __restrict__ ei, float* __restrict__ PL, int* __restrict__ cnt)
{
  __shared__ float wp[384];
  const int t = threadIdx.x;
  for (int i = t; i < 384; i += 256) wp[i] = Wpair[i] * 0.57735026919f;
  __syncthreads();
  int e0 = blockIdx.x * 64;
  if (t < 64) {
    int e = e0 + t;
    if (e < EE) atomicAdd(&cnt[ei[e]], 1);
  }
  #pragma unroll
  for (int u = 0; u < 3; u++) {
    int idx = t + 256*u;
    int q = idx / 12, h = idx - 12*q;
    int e = e0 + q;
    if (q < 64 && e < EE) {
      const float* zr = z + (size_t)e*32;
      float s = 0.f;
      #pragma unroll
      for (int c = 0; c < 32; c++) s += zr[c] * wp[c*12 + h];
      PL[(size_t)e*12 + h] = s;
    }
  }
}

// ---------------- CSR build
__global__ __launch_bounds__(1024) void scan_csr(const int* __restrict__ cnt,
                                                 int* __restrict__ rowptr,
                                                 int* __restrict__ cursor)
{
  __shared__ int part[1024];
  int t = threadIdx.x;
  int base = t*20;
  int loc[20];
  int s = 0;
  #pragma unroll
  for (int i = 0; i < 20; i++) {
    int idx = base + i;
    int cc = (idx < NN) ? cnt[idx] : 0;
    loc[i] = s; s += cc;
  }
  part[t] = s;
  __syncthreads();
  for (int off = 1; off < 1024; off <<= 1) {
    int v = (t >= off) ? part[t-off] : 0;
    __syncthreads();
    part[t] += v;
    __syncthreads();
  }
  int pre = (t == 0) ? 0 : part[t-1];
  #pragma unroll
  for (int i = 0; i < 20; i++) {
    int idx = base + i;
    if (idx < NN) { rowptr[idx] = pre + loc[i]; cursor[idx] = pre + loc[i]; }
  }
  if (t == 1023) rowptr[NN] = part[1023];
}

__global__ void fill_csr(const int* __restrict__ ei, int* __restrict__ cursor,
                         int* __restrict__ eidx, int* __restrict__ dstE)
{
  int e = blockIdx.x*256 + threadIdx.x;
  if (e >= EE) return;
  int pos = atomicAdd(&cursor[ei[e]], 1);
  eidx[pos] = e;
  dstE[pos] = ei[EE + e];
}

__device__ __forceinline__ float dot8(const float* qr, uint4 v) {
  float s;
  s  = qr[0]*b2f((unsigned short)(v.x & 0xffffu));
  s += qr[1]*b2f((unsigned short)(v.x >> 16));
  s += qr[2]*b2f((unsigned short)(v.y & 0xffffu));
  s += qr[3]*b2f((unsigned short)(v.y >> 16));
  s += qr[4]*b2f((unsigned short)(v.z & 0xffffu));
  s += qr[5]*b2f((unsigned short)(v.z >> 16));
  s += qr[6]*b2f((unsigned short)(v.w & 0xffffu));
  s += qr[7]*b2f((unsigned short)(v.w >> 16));
  return s;
}

// ---------------- wave-per-node fused attention (r13-proven single-edge body)
__global__ __launch_bounds__(256) void attn_wave(
    const __hip_bfloat16* __restrict__ QE,
    const __hip_bfloat16* __restrict__ KE,
    const __hip_bfloat16* __restrict__ VE,
    const float* __restrict__ z, const float* __restrict__ PL,
    const int* __restrict__ rowptr, const int* __restrict__ eidx,
    const int* __restrict__ dstE,
    const float* __restrict__ R, const float* __restrict__ tr,
    __hip_bfloat16* __restrict__ featB)
{
  __shared__ float sAgg[4][288];
  const int wid = threadIdx.x >> 6, lane = threadIdx.x & 63;
  const int n = blockIdx.x*4 + wid;

  float q0[8], q1[8];
  {
    const uint4* qrow = (const uint4*)(QE + (size_t)n*QE_COLS);
    uint4 Q0 = qrow[lane];
    q0[0]=b2f((unsigned short)(Q0.x&0xffffu)); q0[1]=b2f((unsigned short)(Q0.x>>16));
    q0[2]=b2f((unsigned short)(Q0.y&0xffffu)); q0[3]=b2f((unsigned short)(Q0.y>>16));
    q0[4]=b2f((unsigned short)(Q0.z&0xffffu)); q0[5]=b2f((unsigned short)(Q0.z>>16));
    q0[6]=b2f((unsigned short)(Q0.w&0xffffu)); q0[7]=b2f((unsigned short)(Q0.w>>16));
    if (lane < 32) {
      uint4 Q1 = qrow[64 + lane];
      q1[0]=b2f((unsigned short)(Q1.x&0xffffu)); q1[1]=b2f((unsigned short)(Q1.x>>16));
      q1[2]=b2f((unsigned short)(Q1.y&0xffffu)); q1[3]=b2f((unsigned short)(Q1.y>>16));
      q1[4]=b2f((unsigned short)(Q1.z&0xffffu)); q1[5]=b2f((unsigned short)(Q1.z>>16));
      q1[6]=b2f((unsigned short)(Q1.w&0xffffu)); q1[7]=b2f((unsigned short)(Q1.w>>16));
    } else {
      #pragma unroll
      for (int j = 0; j < 8; j++) q1[j] = 0.f;
    }
  }

  const int myh0 = (lane < 48) ? (lane >> 2) : ((8*lane - 384) / 24);
  const int myh1 = (128 + 8*lane) / 24;

  float mreg = -1e30f, sreg = 0.f;
  float accV0[8] = {}, accV1[8] = {}, accZ[12] = {};

  const int beg = rowptr[n], end = rowptr[n+1];
  for (int c0 = beg; c0 < end; c0 += 64) {
    const int cn = min(64, end - c0);
    int eL = (lane < cn) ? eidx[c0 + lane] : 0;
    int dL = (lane < cn) ? dstE[c0 + lane] : 0;
    for (int j = 0; j < cn; j++) {
      const int e   = __shfl(eL, j);
      const int dst = __shfl(dL, j);
      const uint4* ke = (const uint4*)(KE + (size_t)dst*KE_COLS);
      uint4 K0 = ke[lane];
      uint4 K1 = make_uint4(0,0,0,0);
      if (lane < 32) K1 = ke[64 + lane];
      const uint4* ve = (const uint4*)(VE + (size_t)dst*VE_COLS);
      uint4 V0 = ve[lane];
      uint4 V1 = make_uint4(0,0,0,0);
      if (lane < 20) V1 = ve[64 + lane];
      float zc = (lane < 32) ? z[(size_t)e*32 + lane] : 0.f;
      float pl = (lane < 12) ? PL[(size_t)e*12 + lane] : 0.f;
      float p0 = dot8(q0, K0);
      p0 += __shfl_xor(p0, 1); p0 += __shfl_xor(p0, 2); p0 += __shfl_xor(p0, 4);
      float p1 = dot8(q1, K1);
      p1 += __shfl_xor(p1, 1); p1 += __shfl_xor(p1, 2); p1 += __shfl_xor(p1, 4);
      float pa = __shfl(p0, (lane & 7) * 8);
      float pb = __shfl(p1, (lane & 3) * 8);
      float lg = ((lane < 8) ? pa : pb) + pl;
      float mn = fmaxf(mreg, lg);
      unsigned long long chg = __ballot(mn > mreg) & 0xFFFull;
      float w = expf(lg - mn);
      float r = expf(mreg - mn);
      mreg = mn;
      sreg = sreg * r + w;
      if (chg) {
        float rv0 = __shfl(r, myh0);
        #pragma unroll
        for (int q2 = 0; q2 < 8; q2++) accV0[q2] *= rv0;
        float rv1 = __shfl(r, myh1);
        if (lane < 20) {
          #pragma unroll
          for (int q2 = 0; q2 < 8; q2++) accV1[q2] *= rv1;
        }
        #pragma unroll
        for (int h = 0; h < 12; h++) accZ[h] *= __shfl(r, h);
      }
      float wv0 = __shfl(w, myh0);
      accV0[0] += wv0 * b2f((unsigned short)(V0.x & 0xffffu));
      accV0[1] += wv0 * b2f((unsigned short)(V0.x >> 16));
      accV0[2] += wv0 * b2f((unsigned short)(V0.y & 0xffffu));
      accV0[3] += wv0 * b2f((unsigned short)(V0.y >> 16));
      accV0[4] += wv0 * b2f((unsigned short)(V0.z & 0xffffu));
      accV0[5] += wv0 * b2f((unsigned short)(V0.z >> 16));
      accV0[6] += wv0 * b2f((unsigned short)(V0.w & 0xffffu));
      accV0[7] += wv0 * b2f((unsigned short)(V0.w >> 16));
      float wv1 = __shfl(w, myh1);
      if (lane < 20) {
        accV1[0] += wv1 * b2f((unsigned short)(V1.x & 0xffffu));
        accV1[1] += wv1 * b2f((unsigned short)(V1.x >> 16));
        accV1[2] += wv1 * b2f((unsigned short)(V1.y & 0xffffu));
        accV1[3] += wv1 * b2f((unsigned short)(V1.y >> 16));
        accV1[4] += wv1 * b2f((unsigned short)(V1.z & 0xffffu));
        accV1[5] += wv1 * b2f((unsigned short)(V1.z >> 16));
        accV1[6] += wv1 * b2f((unsigned short)(V1.w & 0xffffu));
        accV1[7] += wv1 * b2f((unsigned short)(V1.w >> 16));
      }
      #pragma unroll
      for (int h = 0; h < 12; h++) accZ[h] += __shfl(w, h) * zc;
    }
  }

  float inv = 0.f;
  if (lane < 12) inv = (sreg > 0.f) ? 1.f/sreg : 0.f;
  __hip_bfloat16* fr = featB + (size_t)n*FCOLS;
  #pragma unroll
  for (int h = 0; h < 12; h++) {
    float iv = __shfl(inv, h);
    if (lane < 32) fr[h*32 + lane] = __float2bfloat16(accZ[h] * iv);
  }
  float iv0 = __shfl(inv, myh0);
  if (lane < 48) {
    uint4 P;
    P.x = (unsigned)f2bu(accV0[0]*iv0) | ((unsigned)f2bu(accV0[1]*iv0) << 16);
    P.y = (unsigned)f2bu(accV0[2]*iv0) | ((unsigned)f2bu(accV0[3]*iv0) << 16);
    P.z = (unsigned)f2bu(accV0[4]*iv0) | ((unsigned)f2bu(accV0[5]*iv0) << 16);
    P.w = (unsigned)f2bu(accV0[6]*iv0) | ((unsigned)f2bu(accV0[7]*iv0) << 16);
    *(uint4*)(fr + 384 + lane*8) = P;
  } else {
    #pragma unroll
    for (int j2 = 0; j2 < 8; j2++) sAgg[wid][(lane-48)*8 + j2] = accV0[j2]*iv0;
  }
  float iv1 = __shfl(inv, myh1);
  if (lane < 20) {
    #pragma unroll
    for (int j2 = 0; j2 < 8; j2++) sAgg[wid][128 + lane*8 + j2] = accV1[j2]*iv1;
  }
  __syncthreads();
  {
    const float* Rn = R + (size_t)n*9;
    float t0 = tr[n*3], t1 = tr[n*3+1], t2 = tr[n*3+2];
    #pragma unroll
    for (int pp = 0; pp < 2; pp++) {
      int pt = lane + pp*64;
      if (pt < 96) {
        float d0 = sAgg[wid][pt*3+0] - t0;
        float d1 = sAgg[wid][pt*3+1] - t1;
        float d2 = sAgg[wid][pt*3+2] - t2;
        float l0 = Rn[0]*d0 + Rn[3]*d1 + Rn[6]*d2;
        float l1 = Rn[1]*d0 + Rn[4]*d1 + Rn[7]*d2;
        float l2 = Rn[2]*d0 + Rn[5]*d1 + Rn[8]*d2;
        float nr = sqrtf(l0*l0 + l1*l1 + l2*l2);
        float ivn = 1.f / fmaxf(nr, 1e-8f);
        fr[768 + pt*3+0] = __float2bfloat16(l0);
        fr[768 + pt*3+1] = __float2bfloat16(l1);
        fr[768 + pt*3+2] = __float2bfloat16(l2);
        fr[1056 + pt]    = __float2bfloat16(nr);
        fr[1152 + pt*3+0] = __float2bfloat16(l0*ivn);
        fr[1152 + pt*3+1] = __float2bfloat16(l1*ivn);
        fr[1152 + pt*3+2] = __float2bfloat16(l2*ivn);
      }
    }
  }
}

// ---------------- fused Wo GEMM + LN1 + MLP(MFMA) + residual + LN2 -> out
__global__ __launch_bounds__(256) void wo_mlp(
    const __hip_bfloat16* __restrict__ featB, const __hip_bfloat16* __restrict__ WoT,
    const float* __restrict__ bo, const float* __restrict__ x,
    const __hip_bfloat16* __restrict__ W1T, const float* __restrict__ bb1,
    const __hip_bfloat16* __restrict__ W2T, const float* __restrict__ bb2,
    const __hip_bfloat16* __restrict__ W3T, const float* __restrict__ bb3,
    const float* __restrict__ g1, const float* __restrict__ b1v,
    const float* __restrict__ g2, const float* __restrict__ b2v,
    float* __restrict__ out)
{
  __shared__ float4 arenaV[3200];   // 51200 bytes, 16B-aligned
  __shared__ float mu_s[64], rs_s[64];
  char* arena  = (char*)arenaV;
  short* A_lds = (short*)arena;
  short* B_lds = (short*)(arena + 13312);
  float* hs    = (float*)arena;
  short* actB  = (short*)(arena + 33792);

  const int t = threadIdx.x;
  const int n0 = blockIdx.x * 64;
  const int lane = t & 63, wid = t >> 6;
  const int wm = wid >> 1, wn = wid & 1;
  const int lrow = lane >> 4, lcol = lane & 15;
  f32x4v zero = {0.f, 0.f, 0.f, 0.f};

  f32x4v acc[2][4];
  #pragma unroll
  for (int i = 0; i < 2; i++)
    #pragma unroll
    for (int j = 0; j < 4; j++) acc[i][j] = zero;
  for (int k0 = 0; k0 < 1440; k0 += 96) {
    __syncthreads();
    {
      int r = t >> 2, kc = (t & 3) * 24;
      int gr = n0 + r; if (gr >= NN) gr = NN-1;
      const uint4* src = (const uint4*)(featB + (size_t)gr*FCOLS + k0 + kc);
      uint4 v0 = src[0], v1 = src[1], v2 = src[2];
      *(uint4*)&A_lds[r*104 + kc +  0] = v0;
      *(uint4*)&A_lds[r*104 + kc +  8] = v1;
      *(uint4*)&A_lds[r*104 + kc + 16] = v2;
    }
    {
      int cI = t >> 1, ko = (t & 1) * 48;
      const uint4* src = (const uint4*)(WoT + (size_t)cI*1440 + k0 + ko);
      #pragma unroll
      for (int j = 0; j < 6; j++)
        *(uint4*)&B_lds[cI*104 + ko + j*8] = src[j];
    }
    __syncthreads();
    #pragma unroll
    for (int ks = 0; ks < 3; ks++) {
      int kb = ks*32 + lrow*8;
      bf16x8v a0 = *(const bf16x8v*)&A_lds[(wm*32 +      lcol)*104 + kb];
      bf16x8v a1 = *(const bf16x8v*)&A_lds[(wm*32 + 16 + lcol)*104 + kb];
      #pragma unroll
      for (int nt = 0; nt < 4; nt++) {
        bf16x8v b = *(const bf16x8v*)&B_lds[(wn*64 + nt*16 + lcol)*104 + kb];
        acc[0][nt] = __builtin_amdgcn_mfma_f32_16x16x32_bf16(a0, b, acc[0][nt], 0, 0, 0);
        acc[1][nt] = __builtin_amdgcn_mfma_f32_16x16x32_bf16(a1, b, acc[1][nt], 0, 0, 0);
      }
    }
  }
  __syncthreads();
  #pragma unroll
  for (int nt = 0; nt < 4; nt++) {
    int col = wn*64 + nt*16 + lcol;
    float bv = bo[col];
    #pragma unroll
    for (int mt = 0; mt < 2; mt++) {
      #pragma unroll
      for (int r = 0; r < 4; r++) {
        int row = wm*32 + mt*16 + lrow*4 + r;
        int gr = n0 + row; if (gr >= NN) gr = NN-1;
        hs[row*132 + col] = acc[mt][nt][r] + bv + x[(size_t)gr*128 + col];
      }
    }
  }
  __syncthreads();
  for (int q = 0; q < 16; q++) {
    int r = wid*16 + q;
    float v0 = hs[r*132 + lane], v1 = hs[r*132 + lane + 64];
    float s = v0 + v1, ss = v0*v0 + v1*v1;
    #pragma unroll
    for (int m2 = 32; m2 >= 1; m2 >>= 1) { s += __shfl_xor(s, m2); ss += __shfl_xor(ss, m2); }
    if (lane == 0) { float mu = s*(1.f/128.f); mu_s[r] = mu; rs_s[r] = rsqrtf(ss*(1.f/128.f) - mu*mu + 1e-5f); }
  }
  __syncthreads();
  for (int e = t; e < 8192; e += 256) {
    int r = e >> 7, c = e & 127;
    float v = (hs[r*132 + c] - mu_s[r]) * rs_s[r] * g1[c] + b1v[c];
    hs[r*132 + c] = v;
    actB[r*136 + c] = (short)f2bu(v);
  }
  __syncthreads();

#define MLP_MFMA_LAYER(WT, BIAS, IS_LAST)                                       \
  {                                                                             \
    f32x4v acc2[2][4];                                                          \
    _Pragma("unroll")                                                           \
    for (int i = 0; i < 2; i++)                                                 \
      _Pragma("unroll")                                                         \
      for (int j = 0; j < 4; j++) acc2[i][j] = zero;                            \
    _Pragma("unroll")                                                           \
    for (int ks = 0; ks < 4; ks++) {                                            \
      int kb = ks*32 + lrow*8;                                                  \
      bf16x8v a0 = *(const bf16x8v*)&actB[(wm*32 +      lcol)*136 + kb];        \
      bf16x8v a1 = *(const bf16x8v*)&actB[(wm*32 + 16 + lcol)*136 + kb];        \
      _Pragma("unroll")                                                         \
      for (int nt = 0; nt < 4; nt++) {                                          \
        int col = wn*64 + nt*16 + lcol;                                         \
        bf16x8v b = *(const bf16x8v*)(WT + (size_t)col*128 + kb);               \
        acc2[0][nt] = __builtin_amdgcn_mfma_f32_16x16x32_bf16(a0, b, acc2[0][nt], 0, 0, 0); \
        acc2[1][nt] = __builtin_amdgcn_mfma_f32_16x16x32_bf16(a1, b, acc2[1][nt], 0, 0, 0); \
      }                                                                         \
    }                                                                           \
    __syncthreads();                                                            \
    _Pragma("unroll")                                                           \
    for (int nt = 0; nt < 4; nt++) {                                            \
      int col = wn*64 + nt*16 + lcol;                                           \
      float bv = BIAS[col];                                                     \
      _Pragma("unroll")                                                         \
      for (int mt = 0; mt < 2; mt++) {                                          \
        _Pragma("unroll")                                                       \
        for (int r = 0; r < 4; r++) {                                           \
          int row = wm*32 + mt*16 + lrow*4 + r;                                 \
          float v = acc2[mt][nt][r] + bv;                                       \
          if (IS_LAST) hs[row*132 + col] += v;                                  \
          else         actB[row*136 + col] = (short)f2bu(fmaxf(v, 0.f));        \
        }                                                                       \
      }                                                                         \
    }                                                                           \
    __syncthreads();                                                            \
  }

  MLP_MFMA_LAYER(W1T, bb1, 0)
  MLP_MFMA_LAYER(W2T, bb2, 0)
  MLP_MFMA_LAYER(W3T, bb3, 1)
#undef MLP_MFMA_LAYER

  for (int q = 0; q < 16; q++) {
    int r = wid*16 + q;
    float v0 = hs[r*132 + lane], v1 = hs[r*132 + lane + 64];
    float s = v0 + v1, ss = v0*v0 + v1*v1;
    #pragma unroll
    for (int m2 = 32; m2 >= 1; m2 >>= 1) { s += __shfl_xor(s, m2); ss += __shfl_xor(ss, m2); }
    if (lane == 0) { float mu = s*(1.f/128.f); mu_s[r] = mu; rs_s[r] = rsqrtf(ss*(1.f/128.f) - mu*mu + 1e-5f); }
  }
  __syncthreads();
  for (int e = t; e < 8192; e += 256) {
    int r = e >> 7, c = e & 127;
    int gr = n0 + r;
    if (gr < NN)
      out[(size_t)gr*128 + c] = (hs[r*132 + c] - mu_s[r]) * rs_s[r] * g2[c] + b2v[c];
  }
}

__global__ void diag_ws(float* out, float v)
{
  if (blockIdx.x == 0 && threadIdx.x == 0) out[0] = v;
}

// ---------------- host side ----------------
static inline size_t alup(size_t v) { return (v + 255) & ~(size_t)255; }

extern "C" void kernel_launch(void* const* d_in, const int* in_sizes, int n_in,
                              void* d_out, int out_size, void* d_ws, size_t ws_size,
                              hipStream_t stream)
{
  const float* R     = (const float*)d_in[0];
  const float* tr    = (const float*)d_in[1];
  const float* x     = (const float*)d_in[2];
  const float* z     = (const float*)d_in[3];
  const int*   ei    = (const int*)  d_in[4];
  const float* Wq    = (const float*)d_in[5];
  const float* Wk    = (const float*)d_in[6];
  const float* Wv    = (const float*)d_in[7];
  const float* Wpair = (const float*)d_in[8];
  const float* spc   = (const float*)d_in[9];
  const float* Wqp   = (const float*)d_in[10];
  const float* Wkp   = (const float*)d_in[11];
  const float* Wvp   = (const float*)d_in[12];
  const float* Wo    = (const float*)d_in[13];
  const float* bo    = (const float*)d_in[14];
  const float* g1    = (const float*)d_in[15];
  const float* b1v   = (const float*)d_in[16];
  const float* w1    = (const float*)d_in[17];
  const float* bb1   = (const float*)d_in[18];
  const float* w2    = (const float*)d_in[19];
  const float* bb2   = (const float*)d_in[20];
  const float* w3    = (const float*)d_in[21];
  const float* bb3   = (const float*)d_in[22];
  const float* g2    = (const float*)d_in[23];
  const float* b2v   = (const float*)d_in[24];
  float* out = (float*)d_out;
  char* ws = (char*)d_ws;

  // region 0: Pqp | Pkp (f32, dead after prep_node) -> reused as featB | PL
  size_t pqp_b = alup((size_t)NN*PQP_COLS*4);
  size_t pkp_b = alup((size_t)NN*PKP_COLS*4);
  size_t region = pqp_b + pkp_b;
  size_t fb_b = alup((size_t)NN*FCOLS*2);
  size_t pl_b = alup((size_t)EE*12*4);
  if (fb_b + pl_b > region) region = fb_b + pl_b;

  float* Pqp = (float*)ws;
  float* Pkp = (float*)(ws + pqp_b);
  __hip_bfloat16* featB = (__hip_bfloat16*)ws;
  float* PL  = (float*)(ws + fb_b);

  size_t off = region;
  __hip_bfloat16* QE = (__hip_bfloat16*)(ws + off); off += alup((size_t)NN*QE_COLS*2);
  __hip_bfloat16* VE = (__hip_bfloat16*)(ws + off); off += alup((size_t)NN*VE_COLS*2);
  __hip_bfloat16* KE = (__hip_bfloat16*)(ws + off); off += alup((size_t)NN*KE_COLS*2);
  int* cnt = (int*)(ws + off);       off += alup((size_t)NN*4);
  int* rowptr = (int*)(ws + off);    off += alup((size_t)(NN+1)*4);
  int* cursor = (int*)(ws + off);    off += alup((size_t)NN*4);
  int* eidx = (int*)(ws + off);      off += alup((size_t)EE*4);
  int* dstE = (int*)(ws + off);      off += alup((size_t)EE*4);
  __hip_bfloat16* WBt = (__hip_bfloat16*)(ws + off); off += alup((size_t)2016*128*2);
  __hip_bfloat16* WoT = (__hip_bfloat16*)(ws + off); off += alup((size_t)128*1440*2);
  __hip_bfloat16* W1T = (__hip_bfloat16*)(ws + off); off += alup((size_t)128*128*2);
  __hip_bfloat16* W2T = (__hip_bfloat16*)(ws + off); off += alup((size_t)128*128*2);
  __hip_bfloat16* W3T = (__hip_bfloat16*)(ws + off); off += alup((size_t)128*128*2);

  if (ws_size < off) {
    diag_ws<<<1, 64, 0, stream>>>(out, (float)((double)ws_size / (1024.0*1024.0)));
    return;
  }

  hipMemsetAsync(cnt, 0, (size_t)NN*4, stream);

  cvt_w<<<(2016*128 + 128*1440 + 3*16384 + 255)/256, 256, 0, stream>>>(
      Wq, Wk, Wv, Wqp, Wkp, Wvp, Wo, w1, w2, w3, WBt, WoT, W1T, W2T, W3T);
  proj_mfma<<<dim3((NN + 63)/64, 4), 256, 0, stream>>>(x, WBt, Pqp, Pkp, QE, KE, VE);
  prep_node<<<NN, 256, 0, stream>>>(Pqp, Pkp, R, tr, spc, QE, KE, VE);
  pl_count<<<(EE + 63)/64, 256, 0, stream>>>(z, Wpair, ei, PL, cnt);
  scan_csr<<<1, 1024, 0, stream>>>(cnt, rowptr, cursor);
  fill_csr<<<EE/256, 256, 0, stream>>>(ei, cursor, eidx, dstE);
  attn_wave<<<NN/4, 256, 0, stream>>>(QE, KE, VE, z, PL, rowptr, eidx, dstE, R, tr, featB);
  wo_mlp<<<(NN + 63)/64, 256, 0, stream>>>(featB, WoT, bo, x,
                                           W1T, bb1, W2T, bb2, W3T, bb3,
                                           g1, b1v, g2, b2v, out);
}